// Round 24
// baseline (159.731 us; speedup 1.0000x reference)
//
#include <hip/hip_runtime.h>
#include <hip/hip_bf16.h>

typedef __attribute__((ext_vector_type(8))) short short8;
typedef float floatx4 __attribute__((ext_vector_type(4)));
typedef float floatx16 __attribute__((ext_vector_type(16)));

#define LQ 4096
#define LK 1024
#define NH 24
#define HD 128
#define HID 3072

__device__ __forceinline__ unsigned short f2bf(float f) {
    __hip_bfloat16 h = __float2bfloat16(f);
    union { __hip_bfloat16 b; unsigned short u; } c; c.b = h;
    return c.u;
}

__device__ __forceinline__ unsigned cvtpk(float a, float b) {
    unsigned r;
    asm("v_cvt_pk_bf16_f32 %0, %1, %2" : "=v"(r) : "v"(a), "v"(b));
    return r;
}

__device__ __forceinline__ float fexp2(float x) {
    float r;
    asm("v_exp_f32 %0, %1" : "=v"(r) : "v"(x));
    return r;
}

// async global->LDS, 16B per lane. LDS dest must be wave-uniform base (HW adds lane*16).
__device__ __forceinline__ void gload16(const void* g, void* l) {
    __builtin_amdgcn_global_load_lds(
        (const __attribute__((address_space(1))) void*)g,
        (__attribute__((address_space(3))) void*)l,
        16, 0, 0);
}

// ---------------- merged f32 -> bf16 convert (latent + Wk + Wv, one dispatch) ----
__global__ void cvt_all(const float* __restrict__ latent, const float* __restrict__ Wk,
                        const float* __restrict__ Wv, unsigned short* __restrict__ lbf,
                        unsigned short* __restrict__ wkbf, unsigned short* __restrict__ wvbf) {
    const int n1 = (LK * HID) / 4;
    const int n2 = (HID * HID) / 4;
    const int total = n1 + 2 * n2;
    int i = blockIdx.x * blockDim.x + threadIdx.x;
    int stride = gridDim.x * blockDim.x;
    for (; i < total; i += stride) {
        const float4* src; ushort4* dst; int j;
        if (i < n1)            { src = (const float4*)latent; dst = (ushort4*)lbf;  j = i; }
        else if (i < n1 + n2)  { src = (const float4*)Wk;     dst = (ushort4*)wkbf; j = i - n1; }
        else                   { src = (const float4*)Wv;     dst = (ushort4*)wvbf; j = i - n1 - n2; }
        float4 v = src[j];
        ushort4 o;
        o.x = f2bf(v.x); o.y = f2bf(v.y); o.z = f2bf(v.z); o.w = f2bf(v.w);
        dst[j] = o;
    }
}

// ---------------- fused projections: BM=64, BN=128(=1 head), full K, 2 matrices --
// grid (384, 2): y=0 -> Wk + RMSNorm+RoPE epilogue -> Kbf;
//                y=1 -> Wv + fragment-order epilogue -> Vfrag (two 8KB kt32 tiles,
//                512 slots each). 768 blocks = 3/CU (48KB LDS), one co-resident
// round. Round-3-proven GEMM core: both operands via gload_lds (source-XOR
// swizzle, linear dest), double-buffered, one barrier per K-step.
__global__ __launch_bounds__(256) void proj_fused(const unsigned short* __restrict__ A,
                                                  const unsigned short* __restrict__ WkB,
                                                  const unsigned short* __restrict__ WvB,
                                                  const float* __restrict__ freqs,
                                                  const float* __restrict__ rmsw,
                                                  unsigned short* __restrict__ Kbf,
                                                  unsigned short* __restrict__ Vfrag) {
    __shared__ __align__(16) unsigned short sh[24576];   // 48KB: As[b]=sh+b*4096, Bs[b]=sh+8192+b*8192
    const int tid = threadIdx.x;
    const int lane = tid & 63;
    const int wave = tid >> 6;
    const int wm = wave >> 1, wn = wave & 1;
    const int mode = blockIdx.y;                 // 0 = K, 1 = V
    const int flat = blockIdx.x;                 // 0..383
    const int wid = (flat & 7) * 48 + (flat >> 3);  // bijective XCD swizzle (384 = 8*48)
    const int lt = wid & 15;                     // l-tile (64 rows)
    const int h  = wid >> 4;                     // head 0..23
    const int bm0 = lt * 64;
    const int bn0 = h * 128;
    const int lr = lane & 15;
    const int lg = lane >> 4;
    const unsigned short* Bw = mode ? WvB : WkB;

    floatx4 acc[2][4];
    for (int i = 0; i < 2; ++i)
        for (int j = 0; j < 4; ++j)
            acc[i][j] = (floatx4){0.f, 0.f, 0.f, 0.f};

    auto stage = [&](int b, int k0) {
        unsigned short* Asb = sh + b * 4096;
        unsigned short* Bsb = sh + 8192 + b * 8192;
        for (int p = 0; p < 2; ++p) {
            int slot = p * 256 + tid;
            int r = slot >> 3, cb = slot & 7;
            int g = cb ^ (r & 7);
            gload16(&A[(bm0 + r) * HID + k0 + g * 8], &Asb[(p * 256 + wave * 64) * 8]);
        }
        for (int p = 0; p < 4; ++p) {
            int slot = p * 256 + tid;
            int r = slot >> 3, cb = slot & 7;
            int g = cb ^ (r & 7);
            gload16(&Bw[(bn0 + r) * HID + k0 + g * 8], &Bsb[(p * 256 + wave * 64) * 8]);
        }
    };

    auto compute = [&](int b) {
        const unsigned short* Asb = sh + b * 4096;
        const unsigned short* Bsb = sh + 8192 + b * 8192;
        for (int ks = 0; ks < 2; ++ks) {
            short8 af[2], bfr[4];
            for (int mt = 0; mt < 2; ++mt) {
                int m = wm * 32 + mt * 16 + lr;
                int sc = (ks * 4 + lg) ^ (m & 7);
                af[mt] = *(const short8*)(&Asb[m * 64 + sc * 8]);
            }
            for (int nt = 0; nt < 4; ++nt) {
                int n = wn * 64 + nt * 16 + lr;
                int sc = (ks * 4 + lg) ^ (n & 7);
                bfr[nt] = *(const short8*)(&Bsb[n * 64 + sc * 8]);
            }
            __builtin_amdgcn_s_setprio(1);
            for (int mt = 0; mt < 2; ++mt)
                for (int nt = 0; nt < 4; ++nt)
                    acc[mt][nt] = __builtin_amdgcn_mfma_f32_16x16x32_bf16(af[mt], bfr[nt], acc[mt][nt], 0, 0, 0);
            __builtin_amdgcn_s_setprio(0);
        }
    };

    stage(0, 0);
    __syncthreads();
    int buf = 0;
    for (int k0 = 0; k0 < HID - 64; k0 += 64) {
        stage(buf ^ 1, k0 + 64);
        compute(buf);
        __syncthreads();
        buf ^= 1;
    }
    compute(buf);
    __syncthreads();   // all waves done with As/Bs -> sh reusable

    // C element: row l_loc = wm*32 + mt*16 + lg*4 + rg, col d = wn*64 + nt*16 + lr
    if (mode == 0) {
        // ---- RMSNorm + RoPE epilogue -> Kbf[l][h*128+d] ----
        float* red = (float*)sh;   // [64][2]
        for (int mt = 0; mt < 2; ++mt)
            for (int rg = 0; rg < 4; ++rg) {
                float s = 0.f;
                for (int nt = 0; nt < 4; ++nt) {
                    float v = acc[mt][nt][rg];
                    s += v * v;
                }
                s += __shfl_xor(s, 1);
                s += __shfl_xor(s, 2);
                s += __shfl_xor(s, 4);
                s += __shfl_xor(s, 8);
                if (lr == 0) red[(wm * 32 + mt * 16 + lg * 4 + rg) * 2 + wn] = s;
            }
        __syncthreads();
        for (int mt = 0; mt < 2; ++mt)
            for (int rg = 0; rg < 4; ++rg) {
                int row = wm * 32 + mt * 16 + lg * 4 + rg;
                float tot = red[row * 2] + red[row * 2 + 1];
                float rsn = rsqrtf(tot * (1.0f / 128.0f) + 1e-6f);
                int l = bm0 + row;
                for (int nt = 0; nt < 4; ++nt) {
                    int d = wn * 64 + nt * 16 + lr;
                    float xn = acc[mt][nt][rg] * rsn * rmsw[d];
                    float f = freqs[l * (HD / 2) + (d >> 1)];
                    float sn = __sinf(f), cs = __cosf(f);
                    float partner = __shfl_xor(xn, 1);  // lane lr^1 holds d^1, same row
                    float o = (d & 1) ? (partner * sn + xn * cs) : (xn * cs - partner * sn);
                    Kbf[l * HID + bn0 + d] = f2bf(o);
                }
            }
    } else {
        // ---- fragment-order V epilogue -> Vfrag tiles (h, kt32 = lt*2 + {0,1}) ----
        float* Ct = (float*)sh;   // [64][132] = 33.8KB (fits 48KB)
        for (int mt = 0; mt < 2; ++mt)
            for (int nt = 0; nt < 4; ++nt)
                for (int rg = 0; rg < 4; ++rg)
                    Ct[(wm * 32 + mt * 16 + lg * 4 + rg) * 132 + wn * 64 + nt * 16 + lr] = acc[mt][nt][rg];
        __syncthreads();
        // emit 2 tiles x 512 slots; slot s = ((ntd*2 + c)*2 + hi)*32 + l31 (s in 0..511)
        for (int p = 0; p < 4; ++p) {
            int slot2 = p * 256 + tid;           // 0..1023
            int tile = slot2 >> 9;               // 0..1
            int s = slot2 & 511;                 // 0..511
            int l31v = s & 31;
            int hi2 = (s >> 5) & 1;
            int c2 = (s >> 6) & 1;
            int ntd = s >> 7;                    // 0..3
            int col = ntd * 32 + l31v;
            int r0 = tile * 32 + c2 * 16 + hi2 * 8;
            short8 v;
            for (int j = 0; j < 8; ++j)
                v[j] = (short)f2bf(Ct[(r0 + j) * 132 + col]);
            unsigned short* dst = Vfrag + (((size_t)(h * 32 + lt * 2 + tile)) << 12);
            *(short8*)(&dst[s * 8]) = v;
        }
    }
}

// ---------------- Flash attention (V direct from global, ONE barrier/phase) ------
// Dual kv-streams. V is NOT LDS-staged: PV reads fragment-order Vfrag straight
// from global — a wave's read is 1KB contiguous (perfectly coalesced), tiles are
// L2-resident (XCD swizzle: 3 heads/XCD = 1.5MB). This deletes the mid-phase
// barrier (V visibility was its only purpose) and 2 of 6 gload16/thread/phase.
// LDS = KA/KB dbuf only (32KB). K staging + end barrier unchanged (r22 lesson:
// keep the barrier-clustered K schedule — L2 coalescing depends on it).
__global__ __launch_bounds__(256, 3) void attn(const float* __restrict__ Q,
                                               const unsigned short* __restrict__ Kbf,
                                               const unsigned short* __restrict__ Vfrag,
                                               float* __restrict__ O) {
    __shared__ __align__(16) unsigned short KA[2][32 * 128];
    __shared__ __align__(16) unsigned short KB[2][32 * 128];
    const int tid = threadIdx.x;
    const int lane = tid & 63;
    const int wave = tid >> 6;
    const int l31 = lane & 31;
    const int hi = lane >> 5;
    const int flat = blockIdx.x + gridDim.x * blockIdx.y;
    const int wid = (flat & 7) * 96 + (flat >> 3);
    const int h = wid >> 5;
    const int q0 = (wid & 31) * 128 + wave * 32;
    const float qscale = 0.08838834764831843f * 1.44269504088896340736f;
    const float SHIFT = 32.0f;

    short8 qf[8];
#pragma unroll
    for (int m = 0; m < 8; ++m) {
        const float* qp = &Q[(q0 + l31) * HID + h * HD + m * 16 + hi * 8];
        float4 lo = *(const float4*)(qp);
        float4 hif = *(const float4*)(qp + 4);
        short8 v;
        v[0] = (short)f2bf(lo.x * qscale);
        v[1] = (short)f2bf(lo.y * qscale);
        v[2] = (short)f2bf(lo.z * qscale);
        v[3] = (short)f2bf(lo.w * qscale);
        v[4] = (short)f2bf(hif.x * qscale);
        v[5] = (short)f2bf(hif.y * qscale);
        v[6] = (short)f2bf(hif.z * qscale);
        v[7] = (short)f2bf(hif.w * qscale);
        qf[m] = v;
    }

    floatx16 accO[4];
#pragma unroll
    for (int i = 0; i < 4; ++i)
#pragma unroll
        for (int r = 0; r < 16; ++r) accO[i][r] = 0.f;
    float psum = 0.f;

    auto stageK = [&](unsigned short* dst, int kt) {
        for (int i = 0; i < 2; ++i) {
            int slot = i * 256 + tid;
            int r = slot >> 4, bb = slot & 15;
            int g = bb ^ (r & 15);
            gload16(&Kbf[(kt * 32 + r) * HID + h * HD + g * 8],
                    &dst[(i * 256 + wave * 64) * 8]);
        }
    };

    auto softmax32 = [&](floatx16 s, short8& pa, short8& pb) {
        float e[16];
#pragma unroll
        for (int r = 0; r < 16; ++r) e[r] = fexp2(s[r]);
        {
            float s01 = e[0] + e[1],   s23 = e[2] + e[3];
            float s45 = e[4] + e[5],   s67 = e[6] + e[7];
            float s89 = e[8] + e[9],   sab = e[10] + e[11];
            float scd = e[12] + e[13], sef = e[14] + e[15];
            float t0 = s01 + s23, t1 = s45 + s67, t2 = s89 + sab, t3 = scd + sef;
            psum += (t0 + t1) + (t2 + t3);
        }
        unsigned d0 = cvtpk(e[0], e[1]),   d1 = cvtpk(e[2], e[3]);
        unsigned d2 = cvtpk(e[4], e[5]),   d3 = cvtpk(e[6], e[7]);
        unsigned d4 = cvtpk(e[8], e[9]),   d5 = cvtpk(e[10], e[11]);
        unsigned d6 = cvtpk(e[12], e[13]), d7 = cvtpk(e[14], e[15]);
        asm volatile("v_permlane32_swap_b32 %0, %1" : "+v"(d0), "+v"(d2));
        asm volatile("v_permlane32_swap_b32 %0, %1" : "+v"(d1), "+v"(d3));
        asm volatile("v_permlane32_swap_b32 %0, %1" : "+v"(d4), "+v"(d6));
        asm volatile("v_permlane32_swap_b32 %0, %1" : "+v"(d5), "+v"(d7));
        union { unsigned u[4]; short8 s; } p0, p1;
        p0.u[0] = d0; p0.u[1] = d1; p0.u[2] = d2; p0.u[3] = d3;
        p1.u[0] = d4; p1.u[1] = d5; p1.u[2] = d6; p1.u[3] = d7;
        pa = p0.s; pb = p1.s;
    };

    stageK(KA[0], 0);
    stageK(KB[0], 16);
    asm volatile("s_waitcnt vmcnt(0)" ::: "memory");
    __builtin_amdgcn_s_barrier();

    for (int t = 0; t < 16; ++t) {
        if (t < 15) {
            stageK(KA[(t + 1) & 1], t + 1);
            stageK(KB[(t + 1) & 1], t + 17);
        }
        floatx16 sA, sB;
#pragma unroll
        for (int r = 0; r < 16; ++r) { sA[r] = -SHIFT; sB[r] = -SHIFT; }
        __builtin_amdgcn_s_setprio(1);
#pragma unroll
        for (int m = 0; m < 8; ++m) {
            int slot = l31 * 16 + ((m * 2 + hi) ^ (l31 & 15));
            short8 kfa = *(const short8*)(&KA[t & 1][slot * 8]);
            short8 kfb = *(const short8*)(&KB[t & 1][slot * 8]);
            sA = __builtin_amdgcn_mfma_f32_32x32x16_bf16(kfa, qf[m], sA, 0, 0, 0);
            sB = __builtin_amdgcn_mfma_f32_32x32x16_bf16(kfb, qf[m], sB, 0, 0, 0);
        }
        __builtin_amdgcn_s_setprio(0);
        short8 pA0, pA1, pB0, pB1;
        softmax32(sA, pA0, pA1);
        softmax32(sB, pB0, pB1);
        // PV: V straight from global (fragment-order: wave reads 1KB contiguous)
        const unsigned short* vA = Vfrag + ((size_t)(h * 32 + t) << 12);
        const unsigned short* vB = Vfrag + ((size_t)(h * 32 + t + 16) << 12);
        __builtin_amdgcn_s_setprio(1);
#pragma unroll
        for (int ntd = 0; ntd < 4; ++ntd) {
            int s0 = ((ntd * 2 + 0) * 2 + hi) * 32 + l31;
            int s1 = ((ntd * 2 + 1) * 2 + hi) * 32 + l31;
            short8 vA0 = *(const short8*)(&vA[s0 * 8]);
            short8 vA1 = *(const short8*)(&vA[s1 * 8]);
            short8 vB0 = *(const short8*)(&vB[s0 * 8]);
            short8 vB1 = *(const short8*)(&vB[s1 * 8]);
            accO[ntd] = __builtin_amdgcn_mfma_f32_32x32x16_bf16(pA0, vA0, accO[ntd], 0, 0, 0);
            accO[ntd] = __builtin_amdgcn_mfma_f32_32x32x16_bf16(pA1, vA1, accO[ntd], 0, 0, 0);
            accO[ntd] = __builtin_amdgcn_mfma_f32_32x32x16_bf16(pB0, vB0, accO[ntd], 0, 0, 0);
            accO[ntd] = __builtin_amdgcn_mfma_f32_32x32x16_bf16(pB1, vB1, accO[ntd], 0, 0, 0);
        }
        __builtin_amdgcn_s_setprio(0);
        __syncthreads();   // K(t+1) landed + visible; KA/KB[t&1] free for overwrite
    }

    float s = psum + __shfl_xor(psum, 32);
    float rinv = 1.0f / s;
    float ri[16];
#pragma unroll
    for (int r = 0; r < 16; ++r) {
        int row = (r & 3) + 8 * (r >> 2) + 4 * hi;
        ri[r] = __shfl(rinv, row);
    }
#pragma unroll
    for (int ntd = 0; ntd < 4; ++ntd)
#pragma unroll
        for (int r = 0; r < 16; ++r) {
            int row = (r & 3) + 8 * (r >> 2) + 4 * hi;
            O[(q0 + row) * HID + h * HD + ntd * 32 + l31] = accO[ntd][r] * ri[r];
        }
}

extern "C" void kernel_launch(void* const* d_in, const int* in_sizes, int n_in,
                              void* d_out, int out_size, void* d_ws, size_t ws_size,
                              hipStream_t stream) {
    const float* Q      = (const float*)d_in[0];
    const float* latent = (const float*)d_in[1];
    const float* freqs  = (const float*)d_in[2];
    const float* Wk     = (const float*)d_in[3];
    const float* Wv     = (const float*)d_in[4];
    const float* rmsw   = (const float*)d_in[5];
    float* out = (float*)d_out;
    char* ws = (char*)d_ws;

    // ws layout (56,623,104 bytes)
    unsigned short* latent_bf = (unsigned short*)(ws);               //  6,291,456
    unsigned short* Wk_bf     = (unsigned short*)(ws + 6291456);     // 18,874,368
    unsigned short* Wv_bf     = (unsigned short*)(ws + 25165824);    // 18,874,368
    unsigned short* Kbf       = (unsigned short*)(ws + 44040192);    //  6,291,456
    unsigned short* Vfrag     = (unsigned short*)(ws + 50331648);    //  6,291,456

    cvt_all<<<2048, 256, 0, stream>>>(latent, Wk, Wv, latent_bf, Wk_bf, Wv_bf);
    proj_fused<<<dim3(384, 2), 256, 0, stream>>>(latent_bf, Wk_bf, Wv_bf, freqs, rmsw, Kbf, Vfrag);
    attn<<<dim3(LQ / 128, NH), 256, 0, stream>>>(Q, Kbf, Vfrag, out);
}

// Round 25
// 134.321 us; speedup vs baseline: 1.1892x; 1.1892x over previous
//
#include <hip/hip_runtime.h>
#include <hip/hip_bf16.h>

typedef __attribute__((ext_vector_type(8))) short short8;
typedef float floatx4 __attribute__((ext_vector_type(4)));
typedef float floatx16 __attribute__((ext_vector_type(16)));

#define LQ 4096
#define LK 1024
#define NH 24
#define HD 128
#define HID 3072

__device__ __forceinline__ unsigned short f2bf(float f) {
    __hip_bfloat16 h = __float2bfloat16(f);
    union { __hip_bfloat16 b; unsigned short u; } c; c.b = h;
    return c.u;
}

__device__ __forceinline__ unsigned cvtpk(float a, float b) {
    unsigned r;
    asm("v_cvt_pk_bf16_f32 %0, %1, %2" : "=v"(r) : "v"(a), "v"(b));
    return r;
}

__device__ __forceinline__ float fexp2(float x) {
    float r;
    asm("v_exp_f32 %0, %1" : "=v"(r) : "v"(x));
    return r;
}

// async global->LDS, 16B per lane. LDS dest must be wave-uniform base (HW adds lane*16).
__device__ __forceinline__ void gload16(const void* g, void* l) {
    __builtin_amdgcn_global_load_lds(
        (const __attribute__((address_space(1))) void*)g,
        (__attribute__((address_space(3))) void*)l,
        16, 0, 0);
}

// ---------------- merged f32 -> bf16 convert (latent + Wk + Wv, one dispatch) ----
__global__ void cvt_all(const float* __restrict__ latent, const float* __restrict__ Wk,
                        const float* __restrict__ Wv, unsigned short* __restrict__ lbf,
                        unsigned short* __restrict__ wkbf, unsigned short* __restrict__ wvbf) {
    const int n1 = (LK * HID) / 4;
    const int n2 = (HID * HID) / 4;
    const int total = n1 + 2 * n2;
    int i = blockIdx.x * blockDim.x + threadIdx.x;
    int stride = gridDim.x * blockDim.x;
    for (; i < total; i += stride) {
        const float4* src; ushort4* dst; int j;
        if (i < n1)            { src = (const float4*)latent; dst = (ushort4*)lbf;  j = i; }
        else if (i < n1 + n2)  { src = (const float4*)Wk;     dst = (ushort4*)wkbf; j = i - n1; }
        else                   { src = (const float4*)Wv;     dst = (ushort4*)wvbf; j = i - n1 - n2; }
        float4 v = src[j];
        ushort4 o;
        o.x = f2bf(v.x); o.y = f2bf(v.y); o.z = f2bf(v.z); o.w = f2bf(v.w);
        dst[j] = o;
    }
}

// ---------------- fused projections: BM=64, BN=128(=1 head), full K, 2 matrices --
// grid (384, 2): y=0 -> Wk + RMSNorm+RoPE epilogue -> Kbf;
//                y=1 -> Wv + fragment-order epilogue -> Vfrag (two 8KB kt32 tiles,
//                512 slots each). 768 blocks = 3/CU (48KB LDS), one co-resident
// round. Round-3-proven GEMM core: both operands via gload_lds (source-XOR
// swizzle, linear dest), double-buffered, one barrier per K-step.
__global__ __launch_bounds__(256) void proj_fused(const unsigned short* __restrict__ A,
                                                  const unsigned short* __restrict__ WkB,
                                                  const unsigned short* __restrict__ WvB,
                                                  const float* __restrict__ freqs,
                                                  const float* __restrict__ rmsw,
                                                  unsigned short* __restrict__ Kbf,
                                                  unsigned short* __restrict__ Vfrag) {
    __shared__ __align__(16) unsigned short sh[24576];   // 48KB: As[b]=sh+b*4096, Bs[b]=sh+8192+b*8192
    const int tid = threadIdx.x;
    const int lane = tid & 63;
    const int wave = tid >> 6;
    const int wm = wave >> 1, wn = wave & 1;
    const int mode = blockIdx.y;                 // 0 = K, 1 = V
    const int flat = blockIdx.x;                 // 0..383
    const int wid = (flat & 7) * 48 + (flat >> 3);  // bijective XCD swizzle (384 = 8*48)
    const int lt = wid & 15;                     // l-tile (64 rows)
    const int h  = wid >> 4;                     // head 0..23
    const int bm0 = lt * 64;
    const int bn0 = h * 128;
    const int lr = lane & 15;
    const int lg = lane >> 4;
    const unsigned short* Bw = mode ? WvB : WkB;

    floatx4 acc[2][4];
    for (int i = 0; i < 2; ++i)
        for (int j = 0; j < 4; ++j)
            acc[i][j] = (floatx4){0.f, 0.f, 0.f, 0.f};

    auto stage = [&](int b, int k0) {
        unsigned short* Asb = sh + b * 4096;
        unsigned short* Bsb = sh + 8192 + b * 8192;
        for (int p = 0; p < 2; ++p) {
            int slot = p * 256 + tid;
            int r = slot >> 3, cb = slot & 7;
            int g = cb ^ (r & 7);
            gload16(&A[(bm0 + r) * HID + k0 + g * 8], &Asb[(p * 256 + wave * 64) * 8]);
        }
        for (int p = 0; p < 4; ++p) {
            int slot = p * 256 + tid;
            int r = slot >> 3, cb = slot & 7;
            int g = cb ^ (r & 7);
            gload16(&Bw[(bn0 + r) * HID + k0 + g * 8], &Bsb[(p * 256 + wave * 64) * 8]);
        }
    };

    auto compute = [&](int b) {
        const unsigned short* Asb = sh + b * 4096;
        const unsigned short* Bsb = sh + 8192 + b * 8192;
        for (int ks = 0; ks < 2; ++ks) {
            short8 af[2], bfr[4];
            for (int mt = 0; mt < 2; ++mt) {
                int m = wm * 32 + mt * 16 + lr;
                int sc = (ks * 4 + lg) ^ (m & 7);
                af[mt] = *(const short8*)(&Asb[m * 64 + sc * 8]);
            }
            for (int nt = 0; nt < 4; ++nt) {
                int n = wn * 64 + nt * 16 + lr;
                int sc = (ks * 4 + lg) ^ (n & 7);
                bfr[nt] = *(const short8*)(&Bsb[n * 64 + sc * 8]);
            }
            __builtin_amdgcn_s_setprio(1);
            for (int mt = 0; mt < 2; ++mt)
                for (int nt = 0; nt < 4; ++nt)
                    acc[mt][nt] = __builtin_amdgcn_mfma_f32_16x16x32_bf16(af[mt], bfr[nt], acc[mt][nt], 0, 0, 0);
            __builtin_amdgcn_s_setprio(0);
        }
    };

    stage(0, 0);
    __syncthreads();
    int buf = 0;
    for (int k0 = 0; k0 < HID - 64; k0 += 64) {
        stage(buf ^ 1, k0 + 64);
        compute(buf);
        __syncthreads();
        buf ^= 1;
    }
    compute(buf);
    __syncthreads();   // all waves done with As/Bs -> sh reusable

    // C element: row l_loc = wm*32 + mt*16 + lg*4 + rg, col d = wn*64 + nt*16 + lr
    if (mode == 0) {
        // ---- RMSNorm + RoPE epilogue -> Kbf[l][h*128+d] ----
        float* red = (float*)sh;   // [64][2]
        for (int mt = 0; mt < 2; ++mt)
            for (int rg = 0; rg < 4; ++rg) {
                float s = 0.f;
                for (int nt = 0; nt < 4; ++nt) {
                    float v = acc[mt][nt][rg];
                    s += v * v;
                }
                s += __shfl_xor(s, 1);
                s += __shfl_xor(s, 2);
                s += __shfl_xor(s, 4);
                s += __shfl_xor(s, 8);
                if (lr == 0) red[(wm * 32 + mt * 16 + lg * 4 + rg) * 2 + wn] = s;
            }
        __syncthreads();
        for (int mt = 0; mt < 2; ++mt)
            for (int rg = 0; rg < 4; ++rg) {
                int row = wm * 32 + mt * 16 + lg * 4 + rg;
                float tot = red[row * 2] + red[row * 2 + 1];
                float rsn = rsqrtf(tot * (1.0f / 128.0f) + 1e-6f);
                int l = bm0 + row;
                for (int nt = 0; nt < 4; ++nt) {
                    int d = wn * 64 + nt * 16 + lr;
                    float xn = acc[mt][nt][rg] * rsn * rmsw[d];
                    float f = freqs[l * (HD / 2) + (d >> 1)];
                    float sn = __sinf(f), cs = __cosf(f);
                    float partner = __shfl_xor(xn, 1);  // lane lr^1 holds d^1, same row
                    float o = (d & 1) ? (partner * sn + xn * cs) : (xn * cs - partner * sn);
                    Kbf[l * HID + bn0 + d] = f2bf(o);
                }
            }
    } else {
        // ---- fragment-order V epilogue -> Vfrag tiles (h, kt32 = lt*2 + {0,1}) ----
        float* Ct = (float*)sh;   // [64][132] = 33.8KB (fits 48KB)
        for (int mt = 0; mt < 2; ++mt)
            for (int nt = 0; nt < 4; ++nt)
                for (int rg = 0; rg < 4; ++rg)
                    Ct[(wm * 32 + mt * 16 + lg * 4 + rg) * 132 + wn * 64 + nt * 16 + lr] = acc[mt][nt][rg];
        __syncthreads();
        // emit 2 tiles x 512 slots; slot s = ((ntd*2 + c)*2 + hi)*32 + l31 (s in 0..511)
        for (int p = 0; p < 4; ++p) {
            int slot2 = p * 256 + tid;           // 0..1023
            int tile = slot2 >> 9;               // 0..1
            int s = slot2 & 511;                 // 0..511
            int l31v = s & 31;
            int hi2 = (s >> 5) & 1;
            int c2 = (s >> 6) & 1;
            int ntd = s >> 7;                    // 0..3
            int col = ntd * 32 + l31v;
            int r0 = tile * 32 + c2 * 16 + hi2 * 8;
            short8 v;
            for (int j = 0; j < 8; ++j)
                v[j] = (short)f2bf(Ct[(r0 + j) * 132 + col]);
            unsigned short* dst = Vfrag + (((size_t)(h * 32 + lt * 2 + tile)) << 12);
            *(short8*)(&dst[s * 8]) = v;
        }
    }
}

// ---------------- Flash attention (round-17/21 structure — best measured) --------
// Dual independent kv-streams per wave (A: tiles 0..15, B: 16..31). Per phase:
// stage V(t), V(t+16), K(t+1), K(t+17); dual-chain QK (independent 8-MFMA chains);
// two sequential softmax32 blocks; __syncthreads (vmcnt0 drain — in this
// L2-resident regime the barrier-clustered schedule IS the optimization: r22
// counted-vmcnt and r24 V-from-global both regressed); PV; end barrier.
// Fixed-shift softmax, cvt_pk + permlane32_swap, fragment-order V (0 bank
// conflicts), s_setprio around MFMA clusters.
__global__ __launch_bounds__(256, 3) void attn(const float* __restrict__ Q,
                                               const unsigned short* __restrict__ Kbf,
                                               const unsigned short* __restrict__ Vfrag,
                                               float* __restrict__ O) {
    __shared__ __align__(16) unsigned short KA[2][32 * 128];
    __shared__ __align__(16) unsigned short KB[2][32 * 128];
    __shared__ __align__(16) unsigned short VA[32 * 128];
    __shared__ __align__(16) unsigned short VB[32 * 128];
    const int tid = threadIdx.x;
    const int lane = tid & 63;
    const int wave = tid >> 6;
    const int l31 = lane & 31;
    const int hi = lane >> 5;
    const int flat = blockIdx.x + gridDim.x * blockIdx.y;
    const int wid = (flat & 7) * 96 + (flat >> 3);
    const int h = wid >> 5;
    const int q0 = (wid & 31) * 128 + wave * 32;
    const float qscale = 0.08838834764831843f * 1.44269504088896340736f;
    const float SHIFT = 32.0f;

    short8 qf[8];
#pragma unroll
    for (int m = 0; m < 8; ++m) {
        const float* qp = &Q[(q0 + l31) * HID + h * HD + m * 16 + hi * 8];
        float4 lo = *(const float4*)(qp);
        float4 hif = *(const float4*)(qp + 4);
        short8 v;
        v[0] = (short)f2bf(lo.x * qscale);
        v[1] = (short)f2bf(lo.y * qscale);
        v[2] = (short)f2bf(lo.z * qscale);
        v[3] = (short)f2bf(lo.w * qscale);
        v[4] = (short)f2bf(hif.x * qscale);
        v[5] = (short)f2bf(hif.y * qscale);
        v[6] = (short)f2bf(hif.z * qscale);
        v[7] = (short)f2bf(hif.w * qscale);
        qf[m] = v;
    }

    floatx16 accO[4];
#pragma unroll
    for (int i = 0; i < 4; ++i)
#pragma unroll
        for (int r = 0; r < 16; ++r) accO[i][r] = 0.f;
    float psum = 0.f;

    auto stageK = [&](unsigned short* dst, int kt) {
        for (int i = 0; i < 2; ++i) {
            int slot = i * 256 + tid;
            int r = slot >> 4, bb = slot & 15;
            int g = bb ^ (r & 15);
            gload16(&Kbf[(kt * 32 + r) * HID + h * HD + g * 8],
                    &dst[(i * 256 + wave * 64) * 8]);
        }
    };
    auto stageV = [&](unsigned short* dst, int kt) {
        const unsigned short* src = Vfrag + ((size_t)(h * 32 + kt) << 12);
        for (int i = 0; i < 2; ++i) {
            int slot = i * 256 + tid;
            gload16(&src[slot * 8], &dst[(i * 256 + wave * 64) * 8]);
        }
    };

    auto softmax32 = [&](floatx16 s, short8& pa, short8& pb) {
        float e[16];
#pragma unroll
        for (int r = 0; r < 16; ++r) e[r] = fexp2(s[r]);
        {
            float s01 = e[0] + e[1],   s23 = e[2] + e[3];
            float s45 = e[4] + e[5],   s67 = e[6] + e[7];
            float s89 = e[8] + e[9],   sab = e[10] + e[11];
            float scd = e[12] + e[13], sef = e[14] + e[15];
            float t0 = s01 + s23, t1 = s45 + s67, t2 = s89 + sab, t3 = scd + sef;
            psum += (t0 + t1) + (t2 + t3);
        }
        unsigned d0 = cvtpk(e[0], e[1]),   d1 = cvtpk(e[2], e[3]);
        unsigned d2 = cvtpk(e[4], e[5]),   d3 = cvtpk(e[6], e[7]);
        unsigned d4 = cvtpk(e[8], e[9]),   d5 = cvtpk(e[10], e[11]);
        unsigned d6 = cvtpk(e[12], e[13]), d7 = cvtpk(e[14], e[15]);
        asm volatile("v_permlane32_swap_b32 %0, %1" : "+v"(d0), "+v"(d2));
        asm volatile("v_permlane32_swap_b32 %0, %1" : "+v"(d1), "+v"(d3));
        asm volatile("v_permlane32_swap_b32 %0, %1" : "+v"(d4), "+v"(d6));
        asm volatile("v_permlane32_swap_b32 %0, %1" : "+v"(d5), "+v"(d7));
        union { unsigned u[4]; short8 s; } p0, p1;
        p0.u[0] = d0; p0.u[1] = d1; p0.u[2] = d2; p0.u[3] = d3;
        p1.u[0] = d4; p1.u[1] = d5; p1.u[2] = d6; p1.u[3] = d7;
        pa = p0.s; pb = p1.s;
    };

    stageK(KA[0], 0);
    stageK(KB[0], 16);
    asm volatile("s_waitcnt vmcnt(0)" ::: "memory");
    __builtin_amdgcn_s_barrier();

    for (int t = 0; t < 16; ++t) {
        stageV(VA, t);
        stageV(VB, t + 16);
        if (t < 15) {
            stageK(KA[(t + 1) & 1], t + 1);
            stageK(KB[(t + 1) & 1], t + 17);
        }
        floatx16 sA, sB;
#pragma unroll
        for (int r = 0; r < 16; ++r) { sA[r] = -SHIFT; sB[r] = -SHIFT; }
        __builtin_amdgcn_s_setprio(1);
#pragma unroll
        for (int m = 0; m < 8; ++m) {
            int slot = l31 * 16 + ((m * 2 + hi) ^ (l31 & 15));
            short8 kfa = *(const short8*)(&KA[t & 1][slot * 8]);
            short8 kfb = *(const short8*)(&KB[t & 1][slot * 8]);
            sA = __builtin_amdgcn_mfma_f32_32x32x16_bf16(kfa, qf[m], sA, 0, 0, 0);
            sB = __builtin_amdgcn_mfma_f32_32x32x16_bf16(kfb, qf[m], sB, 0, 0, 0);
        }
        __builtin_amdgcn_s_setprio(0);
        short8 pA0, pA1, pB0, pB1;
        softmax32(sA, pA0, pA1);
        softmax32(sB, pB0, pB1);
        __syncthreads();
        __builtin_amdgcn_s_setprio(1);
#pragma unroll
        for (int ntd = 0; ntd < 4; ++ntd) {
            int s0 = ((ntd * 2 + 0) * 2 + hi) * 32 + l31;
            int s1 = ((ntd * 2 + 1) * 2 + hi) * 32 + l31;
            short8 vA0 = *(const short8*)(&VA[s0 * 8]);
            short8 vA1 = *(const short8*)(&VA[s1 * 8]);
            short8 vB0 = *(const short8*)(&VB[s0 * 8]);
            short8 vB1 = *(const short8*)(&VB[s1 * 8]);
            accO[ntd] = __builtin_amdgcn_mfma_f32_32x32x16_bf16(pA0, vA0, accO[ntd], 0, 0, 0);
            accO[ntd] = __builtin_amdgcn_mfma_f32_32x32x16_bf16(pA1, vA1, accO[ntd], 0, 0, 0);
            accO[ntd] = __builtin_amdgcn_mfma_f32_32x32x16_bf16(pB0, vB0, accO[ntd], 0, 0, 0);
            accO[ntd] = __builtin_amdgcn_mfma_f32_32x32x16_bf16(pB1, vB1, accO[ntd], 0, 0, 0);
        }
        __builtin_amdgcn_s_setprio(0);
        __syncthreads();
    }

    float s = psum + __shfl_xor(psum, 32);
    float rinv = 1.0f / s;
    float ri[16];
#pragma unroll
    for (int r = 0; r < 16; ++r) {
        int row = (r & 3) + 8 * (r >> 2) + 4 * hi;
        ri[r] = __shfl(rinv, row);
    }
#pragma unroll
    for (int ntd = 0; ntd < 4; ++ntd)
#pragma unroll
        for (int r = 0; r < 16; ++r) {
            int row = (r & 3) + 8 * (r >> 2) + 4 * hi;
            O[(q0 + row) * HID + h * HD + ntd * 32 + l31] = accO[ntd][r] * ri[r];
        }
}

extern "C" void kernel_launch(void* const* d_in, const int* in_sizes, int n_in,
                              void* d_out, int out_size, void* d_ws, size_t ws_size,
                              hipStream_t stream) {
    const float* Q      = (const float*)d_in[0];
    const float* latent = (const float*)d_in[1];
    const float* freqs  = (const float*)d_in[2];
    const float* Wk     = (const float*)d_in[3];
    const float* Wv     = (const float*)d_in[4];
    const float* rmsw   = (const float*)d_in[5];
    float* out = (float*)d_out;
    char* ws = (char*)d_ws;

    // ws layout (56,623,104 bytes)
    unsigned short* latent_bf = (unsigned short*)(ws);               //  6,291,456
    unsigned short* Wk_bf     = (unsigned short*)(ws + 6291456);     // 18,874,368
    unsigned short* Wv_bf     = (unsigned short*)(ws + 25165824);    // 18,874,368
    unsigned short* Kbf       = (unsigned short*)(ws + 44040192);    //  6,291,456
    unsigned short* Vfrag     = (unsigned short*)(ws + 50331648);    //  6,291,456

    cvt_all<<<2048, 256, 0, stream>>>(latent, Wk, Wv, latent_bf, Wk_bf, Wv_bf);
    proj_fused<<<dim3(384, 2), 256, 0, stream>>>(latent_bf, Wk_bf, Wv_bf, freqs, rmsw, Kbf, Vfrag);
    attn<<<dim3(LQ / 128, NH), 256, 0, stream>>>(Q, Kbf, Vfrag, out);
}